// Round 9
// baseline (839.414 us; speedup 1.0000x reference)
//
#include <hip/hip_runtime.h>
#include <hip/hip_bf16.h>
#include <stdint.h>

#define M_DIM 16384   // B*S = 4*4096
#define N_DIM 4096    // OUT
#define K_DIM 4096    // IN
#define NT    (K_DIM / 64)   // 64 K-tiles of BK=64

typedef float f32x4  __attribute__((ext_vector_type(4)));
typedef short bf16x8 __attribute__((ext_vector_type(8)));
typedef unsigned short u16;

__device__ __forceinline__ unsigned short f32_to_bf16(float f) {
    union { float f; uint32_t u; } v; v.f = f;
    uint32_t u = v.u;
    uint32_t r = (u + 0x7FFFu + ((u >> 16) & 1u)) >> 16;   // RNE
    return (unsigned short)r;
}

__device__ __forceinline__ void gload16(const void* g, void* l) {
    __builtin_amdgcn_global_load_lds(
        (const __attribute__((address_space(1))) void*)g,
        (__attribute__((address_space(3))) void*)l,
        16, 0, 0);
}

// ---------------------------------------------------------------------------
// Fused prep: blocks [0,16384): Weff build; blocks [16384,49152): x cvt.
// Weff[o][i] = bf16( W0[o][i] + 0.25 * w1[o>>6][i>>6] * w2[o&63][i&63] )
// ---------------------------------------------------------------------------
__global__ void prep(const float* __restrict__ W0,
                     const float* __restrict__ w1,
                     const float* __restrict__ w2a,
                     const float* __restrict__ w2b,
                     const float* __restrict__ x,
                     u16* __restrict__ Weff,
                     u16* __restrict__ xb) {
    const int bid = blockIdx.x;
    if (bid < 16384) {
        long idx = (long)bid * 256 + threadIdx.x;   // over N*K/4
        long e0 = idx * 4;
        int o  = (int)(e0 >> 12);
        int i0 = (int)(e0 & 4095);
        int r  = o & 63;
        float a0 = w2a[r * 4 + 0], a1 = w2a[r * 4 + 1];
        float a2 = w2a[r * 4 + 2], a3 = w2a[r * 4 + 3];
        float w1v = w1[(o >> 6) * 64 + (i0 >> 6)] * 0.25f;
        float4 w0 = *(const float4*)(W0 + e0);
        const float* w0p = (const float*)&w0;
        unsigned short outp[4];
#pragma unroll
        for (int j = 0; j < 4; ++j) {
            int c = (i0 + j) & 63;
            float w2 = a0 * w2b[0 * 64 + c] + a1 * w2b[1 * 64 + c]
                     + a2 * w2b[2 * 64 + c] + a3 * w2b[3 * 64 + c];
            outp[j] = f32_to_bf16(w0p[j] + w1v * w2);
        }
        *(ushort4*)(Weff + e0) = make_ushort4(outp[0], outp[1], outp[2], outp[3]);
    } else {
        long idx = (long)(bid - 16384) * 256 + threadIdx.x;   // over M*K/8
        long e0 = idx * 8;
        float4 v0 = *(const float4*)(x + e0);
        float4 v1 = *(const float4*)(x + e0 + 4);
        union { unsigned short s[8]; int4 v; } o;
        const float* p0 = (const float*)&v0;
        const float* p1 = (const float*)&v1;
#pragma unroll
        for (int j = 0; j < 4; ++j) o.s[j]     = f32_to_bf16(p0[j]);
#pragma unroll
        for (int j = 0; j < 4; ++j) o.s[4 + j] = f32_to_bf16(p1[j]);
        *(int4*)(xb + e0) = o.v;
    }
}

// ---------------------------------------------------------------------------
// GEMM: 256x256 tile, BK=64, FOUR waves (2Mx2N, 128x128 each), 16x16x32 MFMA.
// LDS fragment reads per tile: 4x32=128 b128 vs 8-wave's 192 — attacks the
// LDS-read-path bound. 2 buffers x 64KB (A+B), depth-1 prefetch,
// one vmcnt(0)+barrier per K-tile, free-flow reads+MFMA.
// C[m][o] = sum_k A[m][k]*B[o][k] + bias[o]
// ---------------------------------------------------------------------------
__global__ __launch_bounds__(256, 1) void gemm_bw(
        const u16* __restrict__ A,    // M x K bf16
        const u16* __restrict__ Bm,   // N x K bf16 (B^T)
        const float* __restrict__ bias,
        float* __restrict__ C) {
    // 2 buffers x [2 ks][256 rows][32 cols] u16 = 2 x 32KB each matrix
    __shared__ __align__(16) u16 ldsA2[2][16384];   // 64 KB
    __shared__ __align__(16) u16 ldsB2[2][16384];   // 64 KB

    const int tid = threadIdx.x;
    const int bid = blockIdx.x;
    // bijective XCD swizzle (nwg = 1024, %8==0)
    const int swz = (bid & 7) * 128 + (bid >> 3);
    const int tm = swz >> 4;          // 64 M-tiles
    const int tn = swz & 15;          // 16 N-tiles
    const int mBase = tm * 256;
    const int nBase = tn * 256;

    const int lane = tid & 63;
    const int wave = tid >> 6;
    const int wr = wave >> 1;         // 0..1  (M half)
    const int wc = wave & 1;          // 0..1  (N half)

    // ---- staging: 16 gloads/thread/tile. srow4 = tid>>2 (0..63), 4 row
    // blocks of 64 rows; swizzle key ((row)>>1)&3 invariant across +64*j ----
    const int srow4 = tid >> 2;
    const int slog = (tid & 3) ^ ((srow4 >> 1) & 3);   // logical 16B slot
    const u16* aSrc = A  + (size_t)(mBase + srow4) * K_DIM + slog * 8;
    const u16* bSrc = Bm + (size_t)(nBase + srow4) * K_DIM + slog * 8;
    const size_t rowStep = (size_t)64 * K_DIM;

    // LDS offset(row, ks, slot) = ks*8192 + row*32 + slot*8 (u16 units)
    // dest for row block j: j*2048 + tid*8 = (j*64+srow4)*32 + (tid&3)*8 ✓
#define STAGE(buf, t) do { const size_t _k = (size_t)(t) * 64;                        \
        _Pragma("unroll")                                                             \
        for (int j = 0; j < 4; ++j) {                                                 \
            gload16(aSrc + j * rowStep + _k,      &ldsA2[buf][j * 2048 + tid * 8]);   \
            gload16(aSrc + j * rowStep + _k + 32, &ldsA2[buf][8192 + j * 2048 + tid * 8]); \
            gload16(bSrc + j * rowStep + _k,      &ldsB2[buf][j * 2048 + tid * 8]);   \
            gload16(bSrc + j * rowStep + _k + 32, &ldsB2[buf][8192 + j * 2048 + tid * 8]); \
        } } while (0)

    // ---- fragment read bases (swizzled) — proven conflict-free pattern ----
    const int rl = lane & 15, cbk = lane >> 4;        // row-in-frag, k-group
    const int sslot = cbk ^ ((rl >> 1) & 3);
    const int aRd = (wr * 128 + rl) * 32 + sslot * 8;  // + m*512 + ks*8192
    const int bRd = (wc * 128 + rl) * 32 + sslot * 8;  // + n*512 + ks*8192

    f32x4 acc[8][8] = {};
    bf16x8 af0, af1, af2, af3, af4, af5, af6, af7;
    bf16x8 bf0, bf1, bf2, bf3, bf4, bf5, bf6, bf7;

#define MM(m, n) acc[m][n] = __builtin_amdgcn_mfma_f32_16x16x32_bf16(af##m, bf##n, acc[m][n], 0, 0, 0)
#define MROW(m) MM(m,0); MM(m,1); MM(m,2); MM(m,3); MM(m,4); MM(m,5); MM(m,6); MM(m,7);

#define KSLICE(pA, pB, s) do {                                                  \
        bf0 = *(const bf16x8*)&pB[(s)*8192 + bRd];                              \
        bf1 = *(const bf16x8*)&pB[(s)*8192 + bRd + 512];                        \
        bf2 = *(const bf16x8*)&pB[(s)*8192 + bRd + 1024];                       \
        bf3 = *(const bf16x8*)&pB[(s)*8192 + bRd + 1536];                       \
        bf4 = *(const bf16x8*)&pB[(s)*8192 + bRd + 2048];                       \
        bf5 = *(const bf16x8*)&pB[(s)*8192 + bRd + 2560];                       \
        bf6 = *(const bf16x8*)&pB[(s)*8192 + bRd + 3072];                       \
        bf7 = *(const bf16x8*)&pB[(s)*8192 + bRd + 3584];                       \
        af0 = *(const bf16x8*)&pA[(s)*8192 + aRd];                              \
        af1 = *(const bf16x8*)&pA[(s)*8192 + aRd + 512];                        \
        af2 = *(const bf16x8*)&pA[(s)*8192 + aRd + 1024];                       \
        af3 = *(const bf16x8*)&pA[(s)*8192 + aRd + 1536];                       \
        af4 = *(const bf16x8*)&pA[(s)*8192 + aRd + 2048];                       \
        af5 = *(const bf16x8*)&pA[(s)*8192 + aRd + 2560];                       \
        af6 = *(const bf16x8*)&pA[(s)*8192 + aRd + 3072];                       \
        af7 = *(const bf16x8*)&pA[(s)*8192 + aRd + 3584];                       \
        __builtin_amdgcn_s_setprio(1);                                          \
        MROW(0) MROW(1) MROW(2) MROW(3)                                         \
        MROW(4) MROW(5) MROW(6) MROW(7)                                         \
        __builtin_amdgcn_s_setprio(0);                                          \
    } while (0)

    // ---- prologue: stage tile 0 into buf 0 ----
    STAGE(0, 0);

    int cur = 0;
    for (int t = 0; t < NT; ++t) {
        // drain own stage(t) (only 16 in flight), certify cross-wave:
        // all stage(t) landed AND all t-1 fragment reads consumed.
        asm volatile("s_waitcnt vmcnt(0)" ::: "memory");
        __builtin_amdgcn_s_barrier();

        // stage t+1 into the other buffer (last read at t-1, pre-barrier)
        const int ts = (t + 1 < NT) ? t + 1 : NT - 1;
        STAGE(cur ^ 1, ts);

        // free-flow: 32 ds_read_b128 + 128 MFMA, compiler-counted lgkmcnt;
        // stage(t+1)'s HBM latency hides under this compute.
        const u16* pA = &ldsA2[cur][0];
        const u16* pB = &ldsB2[cur][0];
        KSLICE(pA, pB, 0);
        KSLICE(pA, pB, 1);
        __builtin_amdgcn_sched_barrier(0);

        cur ^= 1;
    }
    asm volatile("s_waitcnt vmcnt(0) lgkmcnt(0)" ::: "memory");

    // ---- epilogue: C/D layout col=lane&15, row=(lane>>4)*4+j ----
#pragma unroll
    for (int n = 0; n < 8; ++n) {
        const int col = nBase + wc * 128 + n * 16 + rl;
        const float bv = bias[col];
#pragma unroll
        for (int m = 0; m < 8; ++m) {
            const int row = mBase + wr * 128 + m * 16 + cbk * 4;
#pragma unroll
            for (int j = 0; j < 4; ++j)
                C[(size_t)(row + j) * N_DIM + col] = acc[m][n][j] + bv;
        }
    }
#undef STAGE
#undef MM
#undef MROW
#undef KSLICE
}

// ---------------------------------------------------------------------------
// Fallback (only if ws_size too small): correct but slow
// ---------------------------------------------------------------------------
__global__ void naive_fallback(const float* __restrict__ x,
                               const float* __restrict__ W0,
                               const float* __restrict__ b,
                               const float* __restrict__ w1,
                               const float* __restrict__ w2a,
                               const float* __restrict__ w2b,
                               float* __restrict__ out) {
    __shared__ float w2s[64 * 64];
    for (int t = threadIdx.x; t < 4096; t += blockDim.x) {
        int rr = t >> 6, cc = t & 63;
        float s = 0.f;
        for (int k = 0; k < 4; ++k) s += w2a[rr * 4 + k] * w2b[k * 64 + cc];
        w2s[t] = s * 0.25f;
    }
    __syncthreads();
    long idx = (long)blockIdx.x * blockDim.x + threadIdx.x;
    int m = (int)(idx >> 12);
    int o = (int)(idx & 4095);
    const float* xr = x + (long)m * K_DIM;
    const float* wrp = W0 + (long)o * K_DIM;
    int ob = (o >> 6) * 64, orr = (o & 63) * 64;
    float acc = 0.f;
    for (int i = 0; i < K_DIM; ++i) {
        float w = wrp[i] + w1[ob + (i >> 6)] * w2s[orr + (i & 63)];
        acc += xr[i] * w;
    }
    out[idx] = acc + b[o];
}

extern "C" void kernel_launch(void* const* d_in, const int* in_sizes, int n_in,
                              void* d_out, int out_size, void* d_ws, size_t ws_size,
                              hipStream_t stream) {
    const float* x   = (const float*)d_in[0];
    const float* W0  = (const float*)d_in[1];
    const float* b   = (const float*)d_in[2];
    const float* w1  = (const float*)d_in[3];
    const float* w2a = (const float*)d_in[4];
    const float* w2b = (const float*)d_in[5];
    float* out = (float*)d_out;

    const size_t xb_bytes = (size_t)M_DIM * K_DIM * 2;   // 128 MB
    const size_t wf_bytes = (size_t)N_DIM * K_DIM * 2;   // 32 MB

    if (ws_size >= xb_bytes + wf_bytes) {
        u16* xb = (u16*)d_ws;
        u16* wf = (u16*)((char*)d_ws + xb_bytes);
        prep<<<49152, 256, 0, stream>>>(W0, w1, w2a, w2b, x, wf, xb);
        gemm_bw<<<(M_DIM / 256) * (N_DIM / 256), 256, 0, stream>>>(xb, wf, b, out);
    } else {
        naive_fallback<<<((long)M_DIM * N_DIM) / 256, 256, 0, stream>>>(
            x, W0, b, w1, w2a, w2b, out);
    }
}

// Round 10
// 561.270 us; speedup vs baseline: 1.4956x; 1.4956x over previous
//
#include <hip/hip_runtime.h>
#include <hip/hip_bf16.h>
#include <stdint.h>

#define M_DIM 16384   // B*S = 4*4096
#define N_DIM 4096    // OUT
#define K_DIM 4096    // IN
#define NT    (K_DIM / 64)   // 64 K-tiles of BK=64

typedef float f32x4 __attribute__((ext_vector_type(4)));
typedef short bf16x8 __attribute__((ext_vector_type(8)));
typedef unsigned short u16;

__device__ __forceinline__ unsigned short f32_to_bf16(float f) {
    union { float f; uint32_t u; } v; v.f = f;
    uint32_t u = v.u;
    uint32_t r = (u + 0x7FFFu + ((u >> 16) & 1u)) >> 16;   // RNE
    return (unsigned short)r;
}

__device__ __forceinline__ void gload16(const void* g, void* l) {
    __builtin_amdgcn_global_load_lds(
        (const __attribute__((address_space(1))) void*)g,
        (__attribute__((address_space(3))) void*)l,
        16, 0, 0);
}

// ---------------------------------------------------------------------------
// Fused prep (grid-stride, 4096 blocks): virtual blocks [0,16384): Weff;
// [16384,49152): x cvt. Read-once f32 inputs use non-temporal loads so the
// L3 stays dedicated to the bf16 xb/wf working set the GEMM re-reads.
// Weff[o][i] = bf16( W0[o][i] + 0.25 * w1[o>>6][i>>6] * w2[o&63][i&63] )
// ---------------------------------------------------------------------------
__global__ void prep(const float* __restrict__ W0,
                     const float* __restrict__ w1,
                     const float* __restrict__ w2a,
                     const float* __restrict__ w2b,
                     const float* __restrict__ x,
                     u16* __restrict__ Weff,
                     u16* __restrict__ xb) {
    for (int vb = blockIdx.x; vb < 49152; vb += gridDim.x) {
        if (vb < 16384) {
            long idx = (long)vb * 256 + threadIdx.x;   // over N*K/4
            long e0 = idx * 4;
            int o  = (int)(e0 >> 12);
            int i0 = (int)(e0 & 4095);
            int r  = o & 63;
            float a0 = w2a[r * 4 + 0], a1 = w2a[r * 4 + 1];
            float a2 = w2a[r * 4 + 2], a3 = w2a[r * 4 + 3];
            float w1v = w1[(o >> 6) * 64 + (i0 >> 6)] * 0.25f;
            f32x4 w0 = __builtin_nontemporal_load((const f32x4*)(W0 + e0));
            unsigned short outp[4];
#pragma unroll
            for (int j = 0; j < 4; ++j) {
                int c = (i0 + j) & 63;
                float w2 = a0 * w2b[0 * 64 + c] + a1 * w2b[1 * 64 + c]
                         + a2 * w2b[2 * 64 + c] + a3 * w2b[3 * 64 + c];
                outp[j] = f32_to_bf16(w0[j] + w1v * w2);
            }
            *(ushort4*)(Weff + e0) = make_ushort4(outp[0], outp[1], outp[2], outp[3]);
        } else {
            long idx = (long)(vb - 16384) * 256 + threadIdx.x;   // over M*K/8
            long e0 = idx * 8;
            f32x4 v0 = __builtin_nontemporal_load((const f32x4*)(x + e0));
            f32x4 v1 = __builtin_nontemporal_load((const f32x4*)(x + e0 + 4));
            union { unsigned short s[8]; int4 v; } o;
#pragma unroll
            for (int j = 0; j < 4; ++j) o.s[j]     = f32_to_bf16(v0[j]);
#pragma unroll
            for (int j = 0; j < 4; ++j) o.s[4 + j] = f32_to_bf16(v1[j]);
            *(int4*)(xb + e0) = o.v;
        }
    }
}

// ---------------------------------------------------------------------------
// GEMM (r3 schedule — best measured): 256x256 tile, BK=64, 8 waves (2Mx4N),
// 16x16x32 MFMA, 8 phases/iter, ONE barrier per phase, compiler-counted
// lgkmcnt, vmcnt(6) gates at p4/p8, conflict-free slot swizzle.
// C stores are NON-TEMPORAL (keep the 256MB output stream out of L3 so the
// 160MB xb+wf working set stays resident).
// C[m][o] = sum_k A[m][k]*B[o][k] + bias[o]
// ---------------------------------------------------------------------------
__global__ __launch_bounds__(512, 2) void gemm_8p(
        const u16* __restrict__ A,    // M x K bf16
        const u16* __restrict__ Bm,   // N x K bf16 (B^T)
        const float* __restrict__ bias,
        float* __restrict__ C) {
    // [buf][kslice][256 rows][32 cols] bf16, 16KB per (buf,kslice) region
    __shared__ __align__(16) u16 ldsA[2][2][8192];
    __shared__ __align__(16) u16 ldsB[2][2][8192];

    const int tid = threadIdx.x;
    const int bid = blockIdx.x;
    // bijective XCD swizzle (nwg = 1024, %8==0)
    const int swz = (bid & 7) * 128 + (bid >> 3);
    const int tm = swz >> 4;          // 64 M-tiles
    const int tn = swz & 15;          // 16 N-tiles
    const int mBase = tm * 256;
    const int nBase = tn * 256;

    const int lane = tid & 63;
    const int wave = tid >> 6;
    const int wr = wave >> 2;         // 0..1  (M half)
    const int wc = wave & 3;          // 0..3  (N quarter)

    // ---- staging (write side): linear LDS dest, inverse-swizzled source ----
    const int srow = tid >> 2;                        // 0..127
    const int slog = (tid & 3) ^ ((srow >> 1) & 3);   // logical 16B slot
    const u16* aS0 = A  + (size_t)(mBase + srow)       * K_DIM + slog * 8;
    const u16* aS1 = A  + (size_t)(mBase + srow + 128) * K_DIM + slog * 8;
    const u16* bS0 = Bm + (size_t)(nBase + srow)       * K_DIM + slog * 8;
    const u16* bS1 = Bm + (size_t)(nBase + srow + 128) * K_DIM + slog * 8;

#define STAGE_A(buf, t, ks) do { const size_t _k = (size_t)(t) * 64 + (ks) * 32; \
        gload16(aS0 + _k, &ldsA[buf][ks][tid * 8]);                              \
        gload16(aS1 + _k, &ldsA[buf][ks][4096 + tid * 8]); } while (0)
#define STAGE_B(buf, t, ks) do { const size_t _k = (size_t)(t) * 64 + (ks) * 32; \
        gload16(bS0 + _k, &ldsB[buf][ks][tid * 8]);                              \
        gload16(bS1 + _k, &ldsB[buf][ks][4096 + tid * 8]); } while (0)

    // ---- fragment read bases (swizzled) ----
    const int rl = lane & 15, cbk = lane >> 4;        // row-in-frag, k-group
    const int sslot = cbk ^ ((rl >> 1) & 3);
    const int aRd = (wr * 128 + rl) * 32 + sslot * 8;  // ushort offset
    const int bRd = (wc * 64  + rl) * 32 + sslot * 8;

#define RD_A(buf, ks, m) (*(const bf16x8*)&ldsA[buf][ks][aRd + (m) * 512])
#define RD_B(buf, ks, n) (*(const bf16x8*)&ldsB[buf][ks][bRd + (n) * 512])

    f32x4 acc[8][4] = {};
    bf16x8 va0, va1, va2, va3, vb0, vb1, vb2, vb3;

#define MFMA_ROW(mh)                                                                  \
    acc[(mh)*4+0][0] = __builtin_amdgcn_mfma_f32_16x16x32_bf16(va0, vb0, acc[(mh)*4+0][0], 0, 0, 0); \
    acc[(mh)*4+0][1] = __builtin_amdgcn_mfma_f32_16x16x32_bf16(va0, vb1, acc[(mh)*4+0][1], 0, 0, 0); \
    acc[(mh)*4+0][2] = __builtin_amdgcn_mfma_f32_16x16x32_bf16(va0, vb2, acc[(mh)*4+0][2], 0, 0, 0); \
    acc[(mh)*4+0][3] = __builtin_amdgcn_mfma_f32_16x16x32_bf16(va0, vb3, acc[(mh)*4+0][3], 0, 0, 0); \
    acc[(mh)*4+1][0] = __builtin_amdgcn_mfma_f32_16x16x32_bf16(va1, vb0, acc[(mh)*4+1][0], 0, 0, 0); \
    acc[(mh)*4+1][1] = __builtin_amdgcn_mfma_f32_16x16x32_bf16(va1, vb1, acc[(mh)*4+1][1], 0, 0, 0); \
    acc[(mh)*4+1][2] = __builtin_amdgcn_mfma_f32_16x16x32_bf16(va1, vb2, acc[(mh)*4+1][2], 0, 0, 0); \
    acc[(mh)*4+1][3] = __builtin_amdgcn_mfma_f32_16x16x32_bf16(va1, vb3, acc[(mh)*4+1][3], 0, 0, 0); \
    acc[(mh)*4+2][0] = __builtin_amdgcn_mfma_f32_16x16x32_bf16(va2, vb0, acc[(mh)*4+2][0], 0, 0, 0); \
    acc[(mh)*4+2][1] = __builtin_amdgcn_mfma_f32_16x16x32_bf16(va2, vb1, acc[(mh)*4+2][1], 0, 0, 0); \
    acc[(mh)*4+2][2] = __builtin_amdgcn_mfma_f32_16x16x32_bf16(va2, vb2, acc[(mh)*4+2][2], 0, 0, 0); \
    acc[(mh)*4+2][3] = __builtin_amdgcn_mfma_f32_16x16x32_bf16(va2, vb3, acc[(mh)*4+2][3], 0, 0, 0); \
    acc[(mh)*4+3][0] = __builtin_amdgcn_mfma_f32_16x16x32_bf16(va3, vb0, acc[(mh)*4+3][0], 0, 0, 0); \
    acc[(mh)*4+3][1] = __builtin_amdgcn_mfma_f32_16x16x32_bf16(va3, vb1, acc[(mh)*4+3][1], 0, 0, 0); \
    acc[(mh)*4+3][2] = __builtin_amdgcn_mfma_f32_16x16x32_bf16(va3, vb2, acc[(mh)*4+3][2], 0, 0, 0); \
    acc[(mh)*4+3][3] = __builtin_amdgcn_mfma_f32_16x16x32_bf16(va3, vb3, acc[(mh)*4+3][3], 0, 0, 0);

#define PHASE0(buf, ks, VM, ...) do {                                   \
        __builtin_amdgcn_s_barrier();                                   \
        va0 = RD_A(buf, ks, 0);                                         \
        vb0 = RD_B(buf, ks, 0); vb1 = RD_B(buf, ks, 1);                 \
        vb2 = RD_B(buf, ks, 2); vb3 = RD_B(buf, ks, 3);                 \
        va1 = RD_A(buf, ks, 1); va2 = RD_A(buf, ks, 2);                 \
        va3 = RD_A(buf, ks, 3);                                         \
        __VA_ARGS__;                                                    \
        __builtin_amdgcn_s_setprio(1);                                  \
        MFMA_ROW(0)                                                     \
        __builtin_amdgcn_s_setprio(0);                                  \
        __builtin_amdgcn_sched_barrier(0);                              \
        if (VM) asm volatile("s_waitcnt vmcnt(6)" ::: "memory");        \
    } while (0)
#define PHASE1(buf, ks, VM, ...) do {                                   \
        __builtin_amdgcn_s_barrier();                                   \
        va0 = RD_A(buf, ks, 4); va1 = RD_A(buf, ks, 5);                 \
        va2 = RD_A(buf, ks, 6); va3 = RD_A(buf, ks, 7);                 \
        __VA_ARGS__;                                                    \
        __builtin_amdgcn_s_setprio(1);                                  \
        MFMA_ROW(1)                                                     \
        __builtin_amdgcn_s_setprio(0);                                  \
        __builtin_amdgcn_sched_barrier(0);                              \
        if (VM) asm volatile("s_waitcnt vmcnt(6)" ::: "memory");        \
    } while (0)

    // ---- prologue: stage tile0 -> buf0, tile1 (B0,A0,B1) -> buf1 ----
    STAGE_B(0, 0, 0); STAGE_A(0, 0, 0); STAGE_B(0, 0, 1); STAGE_A(0, 0, 1);
    asm volatile("s_waitcnt vmcnt(4)" ::: "memory");
    STAGE_B(1, 1, 0); STAGE_A(1, 1, 0); STAGE_B(1, 1, 1);
    asm volatile("s_waitcnt vmcnt(6)" ::: "memory");

    // ---- main loop: 32 iterations x 2 K-tiles, 8 phases each ----
    for (int it = 0; it < NT / 2; ++it) {
        const int t1 = 2 * it + 1;                            // A1(t1) staged p1
        const int t2 = (2 * it + 2 < NT) ? 2 * it + 2 : NT - 1;
        const int t3 = (2 * it + 3 < NT) ? 2 * it + 3 : NT - 1;
        PHASE0(0, 0, 0, STAGE_A(1, t1, 1));   // p1
        PHASE1(0, 0, 0, STAGE_B(0, t2, 0));   // p2
        PHASE0(0, 1, 0, STAGE_A(0, t2, 0));   // p3
        PHASE1(0, 1, 1, STAGE_B(0, t2, 1));   // p4  vmcnt(6)
        PHASE0(1, 0, 0, STAGE_A(0, t2, 1));   // p5
        PHASE1(1, 0, 0, STAGE_B(1, t3, 0));   // p6
        PHASE0(1, 1, 0, STAGE_A(1, t3, 0));   // p7
        PHASE1(1, 1, 1, STAGE_B(1, t3, 1));   // p8  vmcnt(6)
    }
    asm volatile("s_waitcnt vmcnt(0) lgkmcnt(0)" ::: "memory");

    // ---- epilogue: C/D layout col=lane&15, row=(lane>>4)*4+j; NT stores ----
#pragma unroll
    for (int n = 0; n < 4; ++n) {
        const int col = nBase + wc * 64 + n * 16 + rl;
        const float bv = bias[col];
#pragma unroll
        for (int m = 0; m < 8; ++m) {
            const int row = mBase + wr * 128 + m * 16 + cbk * 4;
#pragma unroll
            for (int j = 0; j < 4; ++j)
                __builtin_nontemporal_store(acc[m][n][j] + bv,
                                            &C[(size_t)(row + j) * N_DIM + col]);
        }
    }
#undef STAGE_A
#undef STAGE_B
#undef RD_A
#undef RD_B
#undef MFMA_ROW
#undef PHASE0
#undef PHASE1
}

// ---------------------------------------------------------------------------
// Fallback (only if ws_size too small): correct but slow
// ---------------------------------------------------------------------------
__global__ void naive_fallback(const float* __restrict__ x,
                               const float* __restrict__ W0,
                               const float* __restrict__ b,
                               const float* __restrict__ w1,
                               const float* __restrict__ w2a,
                               const float* __restrict__ w2b,
                               float* __restrict__ out) {
    __shared__ float w2s[64 * 64];
    for (int t = threadIdx.x; t < 4096; t += blockDim.x) {
        int rr = t >> 6, cc = t & 63;
        float s = 0.f;
        for (int k = 0; k < 4; ++k) s += w2a[rr * 4 + k] * w2b[k * 64 + cc];
        w2s[t] = s * 0.25f;
    }
    __syncthreads();
    long idx = (long)blockIdx.x * blockDim.x + threadIdx.x;
    int m = (int)(idx >> 12);
    int o = (int)(idx & 4095);
    const float* xr = x + (long)m * K_DIM;
    const float* wrp = W0 + (long)o * K_DIM;
    int ob = (o >> 6) * 64, orr = (o & 63) * 64;
    float acc = 0.f;
    for (int i = 0; i < K_DIM; ++i) {
        float w = wrp[i] + w1[ob + (i >> 6)] * w2s[orr + (i & 63)];
        acc += xr[i] * w;
    }
    out[idx] = acc + b[o];
}

extern "C" void kernel_launch(void* const* d_in, const int* in_sizes, int n_in,
                              void* d_out, int out_size, void* d_ws, size_t ws_size,
                              hipStream_t stream) {
    const float* x   = (const float*)d_in[0];
    const float* W0  = (const float*)d_in[1];
    const float* b   = (const float*)d_in[2];
    const float* w1  = (const float*)d_in[3];
    const float* w2a = (const float*)d_in[4];
    const float* w2b = (const float*)d_in[5];
    float* out = (float*)d_out;

    const size_t xb_bytes = (size_t)M_DIM * K_DIM * 2;   // 128 MB
    const size_t wf_bytes = (size_t)N_DIM * K_DIM * 2;   // 32 MB

    if (ws_size >= xb_bytes + wf_bytes) {
        u16* xb = (u16*)d_ws;
        u16* wf = (u16*)((char*)d_ws + xb_bytes);
        prep<<<4096, 256, 0, stream>>>(W0, w1, w2a, w2b, x, wf, xb);
        gemm_8p<<<(M_DIM / 256) * (N_DIM / 256), 512, 0, stream>>>(xb, wf, b, out);
    } else {
        naive_fallback<<<((long)M_DIM * N_DIM) / 256, 256, 0, stream>>>(
            x, W0, b, w1, w2a, w2b, out);
    }
}